// Round 1
// baseline (406.923 us; speedup 1.0000x reference)
//
#include <hip/hip_runtime.h>

#define FDIM 128
#define F2   64   // float2 per row
#define F4   32   // float4 per row

// ---------------- CSR build ----------------

__global__ void zero_kernel(int* __restrict__ p, int n) {
  int i = blockIdx.x * blockDim.x + threadIdx.x;
  if (i < n) p[i] = 0;
}

__global__ void hist_kernel(const int* __restrict__ dst, int* __restrict__ deg, int E) {
  int e = blockIdx.x * blockDim.x + threadIdx.x;
  if (e < E) atomicAdd(&deg[dst[e]], 1);
}

// chunk = 1024 consecutive deg entries per block -> csums[b]
__global__ void scan1_kernel(const int* __restrict__ deg, int* __restrict__ csums, int N) {
  __shared__ int sh[256];
  int t = threadIdx.x, b = blockIdx.x;
  int base = b * 1024;
  int s = 0;
#pragma unroll
  for (int i = 0; i < 4; i++) {
    int idx = base + t + 256 * i;
    if (idx < N) s += deg[idx];
  }
  sh[t] = s; __syncthreads();
  for (int off = 128; off > 0; off >>= 1) {
    if (t < off) sh[t] += sh[t + off];
    __syncthreads();
  }
  if (t == 0) csums[b] = sh[0];
}

__global__ void scan2_kernel(const int* __restrict__ csums, int* __restrict__ coffs, int nchunk) {
  if (threadIdx.x == 0 && blockIdx.x == 0) {
    int run = 0;
    for (int i = 0; i < nchunk; i++) { coffs[i] = run; run += csums[i]; }
  }
}

__global__ void scan3_kernel(const int* __restrict__ deg, const int* __restrict__ coffs,
                             int* __restrict__ row_start, int* __restrict__ fill_pos, int N) {
  __shared__ int sh[256];
  int t = threadIdx.x, b = blockIdx.x;
  int base = b * 1024 + t * 4;
  int d0 = (base + 0 < N) ? deg[base + 0] : 0;
  int d1 = (base + 1 < N) ? deg[base + 1] : 0;
  int d2 = (base + 2 < N) ? deg[base + 2] : 0;
  int d3 = (base + 3 < N) ? deg[base + 3] : 0;
  int l1 = d0, l2 = l1 + d1, l3 = l2 + d2, tot = l3 + d3;
  sh[t] = tot; __syncthreads();
  for (int off = 1; off < 256; off <<= 1) {
    int v = (t >= off) ? sh[t - off] : 0;
    __syncthreads();
    sh[t] += v;
    __syncthreads();
  }
  int excl = sh[t] - tot + coffs[b];
  if (base + 0 < N) { row_start[base + 0] = excl;      fill_pos[base + 0] = excl; }
  if (base + 1 < N) { row_start[base + 1] = excl + l1; fill_pos[base + 1] = excl + l1; }
  if (base + 2 < N) { row_start[base + 2] = excl + l2; fill_pos[base + 2] = excl + l2; }
  if (base + 3 < N) { row_start[base + 3] = excl + l3; fill_pos[base + 3] = excl + l3; }
}

__global__ void place_kernel(const int* __restrict__ src, const int* __restrict__ dst,
                             int* __restrict__ fill_pos, int* __restrict__ ssrc, int E) {
  int e = blockIdx.x * blockDim.x + threadIdx.x;
  if (e < E) {
    int d = dst[e];
    int p = atomicAdd(&fill_pos[d], 1);
    ssrc[p] = src[e];
  }
}

// ---------------- aggregation (one wave per node) ----------------

// out[i] = x[i] + sum_{j in N(i)} x[j]
__global__ void agg1_kernel(const float2* __restrict__ x2, const int* __restrict__ row_start,
                            const int* __restrict__ deg, const int* __restrict__ ssrc,
                            float2* __restrict__ out2, int N) {
  int wave = (blockIdx.x * blockDim.x + threadIdx.x) >> 6;
  int lane = threadIdx.x & 63;
  if (wave >= N) return;
  float2 acc = x2[(size_t)wave * F2 + lane];
  float2 accb = make_float2(0.f, 0.f);
  int start = row_start[wave], d = deg[wave];
  int k = 0;
  for (; k + 1 < d; k += 2) {
    int s0 = ssrc[start + k], s1 = ssrc[start + k + 1];
    float2 v0 = x2[(size_t)s0 * F2 + lane];
    float2 v1 = x2[(size_t)s1 * F2 + lane];
    acc.x += v0.x; acc.y += v0.y;
    accb.x += v1.x; accb.y += v1.y;
  }
  if (k < d) {
    int s0 = ssrc[start + k];
    float2 v0 = x2[(size_t)s0 * F2 + lane];
    acc.x += v0.x; acc.y += v0.y;
  }
  acc.x += accb.x; acc.y += accb.y;
  out2[(size_t)wave * F2 + lane] = acc;
}

// out[i] = a ⊙ (h[i] + sum_{j} h[j]) + (deg+1) ⊙ c      (BN1 folded in)
__global__ void agg2_kernel(const float2* __restrict__ h2, const int* __restrict__ row_start,
                            const int* __restrict__ deg, const int* __restrict__ ssrc,
                            const float* __restrict__ a, const float* __restrict__ c,
                            float2* __restrict__ out2, int N) {
  int wave = (blockIdx.x * blockDim.x + threadIdx.x) >> 6;
  int lane = threadIdx.x & 63;
  if (wave >= N) return;
  float2 acc = h2[(size_t)wave * F2 + lane];
  float2 accb = make_float2(0.f, 0.f);
  int start = row_start[wave], d = deg[wave];
  int k = 0;
  for (; k + 1 < d; k += 2) {
    int s0 = ssrc[start + k], s1 = ssrc[start + k + 1];
    float2 v0 = h2[(size_t)s0 * F2 + lane];
    float2 v1 = h2[(size_t)s1 * F2 + lane];
    acc.x += v0.x; acc.y += v0.y;
    accb.x += v1.x; accb.y += v1.y;
  }
  if (k < d) {
    int s0 = ssrc[start + k];
    float2 v0 = h2[(size_t)s0 * F2 + lane];
    acc.x += v0.x; acc.y += v0.y;
  }
  acc.x += accb.x; acc.y += accb.y;
  float2 av = ((const float2*)a)[lane];
  float2 cv = ((const float2*)c)[lane];
  float dn = (float)(d + 1);
  float2 r;
  r.x = av.x * acc.x + dn * cv.x;
  r.y = av.y * acc.y + dn * cv.y;
  out2[(size_t)wave * F2 + lane] = r;
}

// ---------------- GEMM (N x 128) @ (128 x 128) + bias, ReLU ----------------
// BM=32 rows/block, 256 threads, 4x4 microtile, K chunked by 64 through LDS.

__global__ __launch_bounds__(256) void gemm_relu_kernel(
    const float* __restrict__ in, const float* __restrict__ W,
    const float* __restrict__ bias, float* __restrict__ out, int N) {
  __shared__ float sW[64 * FDIM];   // 32 KB: K-chunk of W
  __shared__ float sIn[32 * FDIM];  // 16 KB: input tile
  int t = threadIdx.x;
  int row0 = blockIdx.x * 32;

  // stage input tile (once): 4096 floats = 1024 float4
  const float4* in4 = (const float4*)in;
  float4* sIn4 = (float4*)sIn;
#pragma unroll
  for (int i = 0; i < 4; i++) {
    int idx = t + 256 * i;            // float4 index; row = idx>>5, col4 = idx&31
    int r = idx >> 5;
    if (row0 + r < N) sIn4[idx] = in4[(size_t)(row0 + r) * F4 + (idx & 31)];
    else sIn4[idx] = make_float4(0.f, 0.f, 0.f, 0.f);
  }

  int tx = t & 31, ty = t >> 5;       // tx: col group (4 cols), ty: row group (4 rows)
  int c0 = tx * 4, r0 = ty * 4;
  float4 acc0 = make_float4(0.f, 0.f, 0.f, 0.f);
  float4 acc1 = acc0, acc2 = acc0, acc3 = acc0;

  const float4* W4 = (const float4*)W;
  float4* sW4 = (float4*)sW;

  for (int kb = 0; kb < FDIM; kb += 64) {
    __syncthreads();  // prior compute done (and sIn staged for kb==0)
#pragma unroll
    for (int i = 0; i < 8; i++) {
      int idx = t + 256 * i;          // 2048 float4 = 8192 floats
      sW4[idx] = W4[kb * F4 + idx];
    }
    __syncthreads();
#pragma unroll
    for (int k = 0; k < 64; k++) {
      float4 wv = *(const float4*)&sW[k * FDIM + c0];
      float a0 = sIn[(r0 + 0) * FDIM + kb + k];
      float a1 = sIn[(r0 + 1) * FDIM + kb + k];
      float a2 = sIn[(r0 + 2) * FDIM + kb + k];
      float a3 = sIn[(r0 + 3) * FDIM + kb + k];
      acc0.x += a0 * wv.x; acc0.y += a0 * wv.y; acc0.z += a0 * wv.z; acc0.w += a0 * wv.w;
      acc1.x += a1 * wv.x; acc1.y += a1 * wv.y; acc1.z += a1 * wv.z; acc1.w += a1 * wv.w;
      acc2.x += a2 * wv.x; acc2.y += a2 * wv.y; acc2.z += a2 * wv.z; acc2.w += a2 * wv.w;
      acc3.x += a3 * wv.x; acc3.y += a3 * wv.y; acc3.z += a3 * wv.z; acc3.w += a3 * wv.w;
    }
  }

  float4 bv = *(const float4*)&bias[c0];
  float4 accs[4] = {acc0, acc1, acc2, acc3};
#pragma unroll
  for (int i = 0; i < 4; i++) {
    int r = row0 + r0 + i;
    if (r < N) {
      float4 o;
      o.x = fmaxf(accs[i].x + bv.x, 0.f);
      o.y = fmaxf(accs[i].y + bv.y, 0.f);
      o.z = fmaxf(accs[i].z + bv.z, 0.f);
      o.w = fmaxf(accs[i].w + bv.w, 0.f);
      *(float4*)&out[(size_t)r * FDIM + c0] = o;
    }
  }
}

// ---------------- BN stats / coeffs / apply ----------------

__global__ void stats_kernel(const float* __restrict__ h, float* __restrict__ sum,
                             float* __restrict__ sq, int N) {
  __shared__ float red[8 * FDIM];
  int t = threadIdx.x;
  int tx = t & 31, ty = t >> 5;
  int c0 = tx * 4;
  float4 s = make_float4(0.f, 0.f, 0.f, 0.f);
  float4 q = s;
  for (int r = blockIdx.x * 8 + ty; r < N; r += gridDim.x * 8) {
    float4 v = *(const float4*)&h[(size_t)r * FDIM + c0];
    s.x += v.x; s.y += v.y; s.z += v.z; s.w += v.w;
    q.x += v.x * v.x; q.y += v.y * v.y; q.z += v.z * v.z; q.w += v.w * v.w;
  }
  *(float4*)&red[ty * FDIM + c0] = s;
  __syncthreads();
  if (t < FDIM) {
    float tot = 0.f;
#pragma unroll
    for (int j = 0; j < 8; j++) tot += red[j * FDIM + t];
    atomicAdd(&sum[t], tot);
  }
  __syncthreads();
  *(float4*)&red[ty * FDIM + c0] = q;
  __syncthreads();
  if (t < FDIM) {
    float tot = 0.f;
#pragma unroll
    for (int j = 0; j < 8; j++) tot += red[j * FDIM + t];
    atomicAdd(&sq[t], tot);
  }
}

__global__ void coeffs_kernel(const float* __restrict__ sum, const float* __restrict__ sq,
                              const float* __restrict__ gamma, const float* __restrict__ beta,
                              float* __restrict__ a, float* __restrict__ c, int N) {
  int t = threadIdx.x;
  if (t < FDIM) {
    float invn = 1.f / (float)N;
    float mean = sum[t] * invn;
    float var = sq[t] * invn - mean * mean;
    float rs = rsqrtf(var + 1e-5f);
    float av = gamma[t] * rs;
    a[t] = av;
    c[t] = beta[t] - mean * av;
  }
}

__global__ void apply_kernel(float* __restrict__ out, const float* __restrict__ a,
                             const float* __restrict__ c, int nvec4) {
  int i = blockIdx.x * blockDim.x + threadIdx.x;
  if (i < nvec4) {
    int c4 = i & (F4 - 1);
    float4 av = ((const float4*)a)[c4];
    float4 cv = ((const float4*)c)[c4];
    float4 v = ((float4*)out)[i];
    v.x = av.x * v.x + cv.x;
    v.y = av.y * v.y + cv.y;
    v.z = av.z * v.z + cv.z;
    v.w = av.w * v.w + cv.w;
    ((float4*)out)[i] = v;
  }
}

// ---------------- launch ----------------

extern "C" void kernel_launch(void* const* d_in, const int* in_sizes, int n_in,
                              void* d_out, int out_size, void* d_ws, size_t ws_size,
                              hipStream_t stream) {
  const float* x   = (const float*)d_in[0];
  const int*   ei  = (const int*)d_in[1];
  const float* W1  = (const float*)d_in[2];
  const float* b1  = (const float*)d_in[3];
  const float* W2  = (const float*)d_in[4];
  const float* b2  = (const float*)d_in[5];
  const float* g1  = (const float*)d_in[6];
  const float* be1 = (const float*)d_in[7];
  const float* g2  = (const float*)d_in[8];
  const float* be2 = (const float*)d_in[9];
  float* out = (float*)d_out;

  const int N = in_sizes[0] / FDIM;
  const int E = in_sizes[1] / 2;
  const int* src = ei;
  const int* dst = ei + E;

  // workspace layout
  char* p = (char*)d_ws;
  int* deg = (int*)p;           p += (size_t)N * 4;
  float* stats = (float*)p;     p += 1024 * 4;   // s1 q1 s2 q2 a1 c1 a2 c2 (128 each)
  int* row_start = (int*)p;     p += (size_t)N * 4;
  int* fill_pos = (int*)p;      p += (size_t)N * 4;
  int* csums = (int*)p;         p += 256 * 4;
  int* coffs = (int*)p;         p += 256 * 4;
  int* ssrc = (int*)p;          p += (size_t)E * 4;
  p = (char*)(((uintptr_t)p + 255) & ~(uintptr_t)255);
  float* tmp = (float*)p;       p += (size_t)N * FDIM * 4;
  float* h1  = (float*)p;       p += (size_t)N * FDIM * 4;

  float* s1 = stats + 0,  *q1 = stats + 128;
  float* s2 = stats + 256, *q2 = stats + 384;
  float* a1 = stats + 512, *c1 = stats + 640;
  float* a2 = stats + 768, *c2 = stats + 896;

  const int nchunk = (N + 1023) / 1024;

  // CSR build
  int zn = N + 1024;  // deg + stats region (contiguous)
  zero_kernel<<<(zn + 255) / 256, 256, 0, stream>>>(deg, zn);
  hist_kernel<<<(E + 255) / 256, 256, 0, stream>>>(dst, deg, E);
  scan1_kernel<<<nchunk, 256, 0, stream>>>(deg, csums, N);
  scan2_kernel<<<1, 64, 0, stream>>>(csums, coffs, nchunk);
  scan3_kernel<<<nchunk, 256, 0, stream>>>(deg, coffs, row_start, fill_pos, N);
  place_kernel<<<(E + 255) / 256, 256, 0, stream>>>(src, dst, fill_pos, ssrc, E);

  // layer 1
  agg1_kernel<<<(N + 3) / 4, 256, 0, stream>>>((const float2*)x, row_start, deg, ssrc,
                                               (float2*)tmp, N);
  gemm_relu_kernel<<<(N + 31) / 32, 256, 0, stream>>>(tmp, W1, b1, h1, N);
  stats_kernel<<<256, 256, 0, stream>>>(h1, s1, q1, N);
  coeffs_kernel<<<1, 128, 0, stream>>>(s1, q1, g1, be1, a1, c1, N);

  // layer 2 (BN1 folded into aggregation)
  agg2_kernel<<<(N + 3) / 4, 256, 0, stream>>>((const float2*)h1, row_start, deg, ssrc,
                                               a1, c1, (float2*)tmp, N);
  gemm_relu_kernel<<<(N + 31) / 32, 256, 0, stream>>>(tmp, W2, b2, out, N);
  stats_kernel<<<256, 256, 0, stream>>>(out, s2, q2, N);
  coeffs_kernel<<<1, 128, 0, stream>>>(s2, q2, g2, be2, a2, c2, N);

  // BN2 in place on out
  int nvec4 = N * F4;
  apply_kernel<<<(nvec4 + 255) / 256, 256, 0, stream>>>(out, a2, c2, nvec4);
}

// Round 2
// 333.397 us; speedup vs baseline: 1.2205x; 1.2205x over previous
//
#include <hip/hip_runtime.h>
#include <hip/hip_fp16.h>

#define FDIM 128

typedef _Float16 half8_t __attribute__((ext_vector_type(8)));
typedef _Float16 half4_t __attribute__((ext_vector_type(4)));
typedef float float4_t __attribute__((ext_vector_type(4)));

// ---------------- CSR build ----------------

__global__ void zero_kernel(int* __restrict__ p, int n) {
  int i = blockIdx.x * blockDim.x + threadIdx.x;
  if (i < n) p[i] = 0;
}

__global__ void hist_kernel(const int* __restrict__ dst, int* __restrict__ deg, int E) {
  int e = blockIdx.x * blockDim.x + threadIdx.x;
  if (e < E) atomicAdd(&deg[dst[e]], 1);
}

__global__ void scan1_kernel(const int* __restrict__ deg, int* __restrict__ csums, int N) {
  __shared__ int sh[256];
  int t = threadIdx.x, b = blockIdx.x;
  int base = b * 1024;
  int s = 0;
#pragma unroll
  for (int i = 0; i < 4; i++) {
    int idx = base + t + 256 * i;
    if (idx < N) s += deg[idx];
  }
  sh[t] = s; __syncthreads();
  for (int off = 128; off > 0; off >>= 1) {
    if (t < off) sh[t] += sh[t + off];
    __syncthreads();
  }
  if (t == 0) csums[b] = sh[0];
}

__global__ void scan2_kernel(const int* __restrict__ csums, int* __restrict__ coffs, int nchunk) {
  if (threadIdx.x == 0 && blockIdx.x == 0) {
    int run = 0;
    for (int i = 0; i < nchunk; i++) { coffs[i] = run; run += csums[i]; }
  }
}

__global__ void scan3_kernel(const int* __restrict__ deg, const int* __restrict__ coffs,
                             int* __restrict__ row_start, int* __restrict__ fill_pos, int N) {
  __shared__ int sh[256];
  int t = threadIdx.x, b = blockIdx.x;
  int base = b * 1024 + t * 4;
  int d0 = (base + 0 < N) ? deg[base + 0] : 0;
  int d1 = (base + 1 < N) ? deg[base + 1] : 0;
  int d2 = (base + 2 < N) ? deg[base + 2] : 0;
  int d3 = (base + 3 < N) ? deg[base + 3] : 0;
  int l1 = d0, l2 = l1 + d1, l3 = l2 + d2, tot = l3 + d3;
  sh[t] = tot; __syncthreads();
  for (int off = 1; off < 256; off <<= 1) {
    int v = (t >= off) ? sh[t - off] : 0;
    __syncthreads();
    sh[t] += v;
    __syncthreads();
  }
  int excl = sh[t] - tot + coffs[b];
  if (base + 0 < N) { row_start[base + 0] = excl;      fill_pos[base + 0] = excl; }
  if (base + 1 < N) { row_start[base + 1] = excl + l1; fill_pos[base + 1] = excl + l1; }
  if (base + 2 < N) { row_start[base + 2] = excl + l2; fill_pos[base + 2] = excl + l2; }
  if (base + 3 < N) { row_start[base + 3] = excl + l3; fill_pos[base + 3] = excl + l3; }
}

__global__ void place_kernel(const int* __restrict__ src, const int* __restrict__ dst,
                             int* __restrict__ fill_pos, int* __restrict__ ssrc, int E) {
  int e = blockIdx.x * blockDim.x + threadIdx.x;
  if (e < E) {
    int d = dst[e];
    int p = atomicAdd(&fill_pos[d], 1);
    ssrc[p] = src[e];
  }
}

// ---------------- convert fp32 -> fp16 ----------------

__global__ void cvt_f2h_kernel(const float* __restrict__ in, _Float16* __restrict__ out, int n4) {
  int i = blockIdx.x * blockDim.x + threadIdx.x;
  if (i < n4) {
    float4 v = ((const float4*)in)[i];
    half4_t h;
    h.x = (_Float16)v.x; h.y = (_Float16)v.y; h.z = (_Float16)v.z; h.w = (_Float16)v.w;
    ((half4_t*)out)[i] = h;
  }
}

// ---------------- aggregation (one wave per node, fp16 rows) ----------------

__device__ inline float2 up2(unsigned u) {
  __half2 h = *(__half2*)&u;
  return __half22float2(h);
}

// out[i] = x[i] + sum_{j in N(i)} x[j]   (fp16 in, fp16 out)
__global__ void agg1_kernel(const unsigned* __restrict__ xu, const int* __restrict__ row_start,
                            const int* __restrict__ deg, const int* __restrict__ ssrc,
                            unsigned* __restrict__ outu, int N) {
  int wave = (blockIdx.x * blockDim.x + threadIdx.x) >> 6;
  int lane = threadIdx.x & 63;
  if (wave >= N) return;
  float2 acc = up2(xu[(size_t)wave * 64 + lane]);
  float2 accb = make_float2(0.f, 0.f);
  int start = row_start[wave], d = deg[wave];
  int k = 0;
  for (; k + 3 < d; k += 4) {
    int s0 = ssrc[start + k], s1 = ssrc[start + k + 1];
    int s2 = ssrc[start + k + 2], s3 = ssrc[start + k + 3];
    unsigned u0 = xu[(size_t)s0 * 64 + lane];
    unsigned u1 = xu[(size_t)s1 * 64 + lane];
    unsigned u2 = xu[(size_t)s2 * 64 + lane];
    unsigned u3 = xu[(size_t)s3 * 64 + lane];
    float2 v0 = up2(u0), v1 = up2(u1), v2 = up2(u2), v3 = up2(u3);
    acc.x += v0.x + v2.x; acc.y += v0.y + v2.y;
    accb.x += v1.x + v3.x; accb.y += v1.y + v3.y;
  }
  for (; k < d; k++) {
    float2 v = up2(xu[(size_t)ssrc[start + k] * 64 + lane]);
    acc.x += v.x; acc.y += v.y;
  }
  acc.x += accb.x; acc.y += accb.y;
  __half2 r = __float22half2_rn(acc);
  outu[(size_t)wave * 64 + lane] = *(unsigned*)&r;
}

// out[i] = a ⊙ (h[i] + sum_j h[j]) + (deg+1) ⊙ c   (BN1 folded; fp16 in/out)
__global__ void agg2_kernel(const unsigned* __restrict__ hu, const int* __restrict__ row_start,
                            const int* __restrict__ deg, const int* __restrict__ ssrc,
                            const float* __restrict__ a, const float* __restrict__ c,
                            unsigned* __restrict__ outu, int N) {
  int wave = (blockIdx.x * blockDim.x + threadIdx.x) >> 6;
  int lane = threadIdx.x & 63;
  if (wave >= N) return;
  float2 acc = up2(hu[(size_t)wave * 64 + lane]);
  float2 accb = make_float2(0.f, 0.f);
  int start = row_start[wave], d = deg[wave];
  int k = 0;
  for (; k + 3 < d; k += 4) {
    int s0 = ssrc[start + k], s1 = ssrc[start + k + 1];
    int s2 = ssrc[start + k + 2], s3 = ssrc[start + k + 3];
    unsigned u0 = hu[(size_t)s0 * 64 + lane];
    unsigned u1 = hu[(size_t)s1 * 64 + lane];
    unsigned u2 = hu[(size_t)s2 * 64 + lane];
    unsigned u3 = hu[(size_t)s3 * 64 + lane];
    float2 v0 = up2(u0), v1 = up2(u1), v2 = up2(u2), v3 = up2(u3);
    acc.x += v0.x + v2.x; acc.y += v0.y + v2.y;
    accb.x += v1.x + v3.x; accb.y += v1.y + v3.y;
  }
  for (; k < d; k++) {
    float2 v = up2(hu[(size_t)ssrc[start + k] * 64 + lane]);
    acc.x += v.x; acc.y += v.y;
  }
  acc.x += accb.x; acc.y += accb.y;
  float2 av = ((const float2*)a)[lane];
  float2 cv = ((const float2*)c)[lane];
  float dn = (float)(d + 1);
  float2 r;
  r.x = av.x * acc.x + dn * cv.x;
  r.y = av.y * acc.y + dn * cv.y;
  __half2 rh = __float22half2_rn(r);
  outu[(size_t)wave * 64 + lane] = *(unsigned*)&rh;
}

// ---------------- MFMA f16 GEMM: (N x 128) @ (128 x 128) + bias, ReLU ----------------
// One 16-row tile per block; 4 waves, each owning 32 cols (2 col-tiles of 16).
// A-frag: A[m = lane&15][k = quad*8 + j]  (16B contiguous load per lane)
// B-frag: B[k = quad*8 + j][n = lane&15]
// C/D:    row = quad*4 + reg, col = lane&15  [m89-verified layout]
template <bool HALF_OUT>
__global__ __launch_bounds__(256) void gemm_mfma_kernel(
    const _Float16* __restrict__ in, const _Float16* __restrict__ W,
    const float* __restrict__ bias, void* __restrict__ out, int N) {
  int t = threadIdx.x;
  int wave = t >> 6, lane = t & 63;
  int quad = lane >> 4, m16 = lane & 15;
  int row0 = blockIdx.x * 16;
  int col0 = wave * 32;

  // B fragments: loaded once, reused for the block's row tile (W is L2-resident)
  half8_t bfrag[2][4];
#pragma unroll
  for (int ct = 0; ct < 2; ct++)
#pragma unroll
    for (int kb = 0; kb < 4; kb++) {
      int col = col0 + ct * 16 + m16;
#pragma unroll
      for (int j = 0; j < 8; j++)
        bfrag[ct][kb][j] = W[(size_t)(kb * 32 + quad * 8 + j) * FDIM + col];
    }

  int arow = row0 + m16;
  if (arow >= N) arow = N - 1;  // safe duplicate read; stores are guarded

  float4_t acc0 = {0.f, 0.f, 0.f, 0.f};
  float4_t acc1 = {0.f, 0.f, 0.f, 0.f};
#pragma unroll
  for (int kb = 0; kb < 4; kb++) {
    half8_t a = *(const half8_t*)(in + (size_t)arow * FDIM + kb * 32 + quad * 8);
    acc0 = __builtin_amdgcn_mfma_f32_16x16x32_f16(a, bfrag[0][kb], acc0, 0, 0, 0);
    acc1 = __builtin_amdgcn_mfma_f32_16x16x32_f16(a, bfrag[1][kb], acc1, 0, 0, 0);
  }

#pragma unroll
  for (int ct = 0; ct < 2; ct++) {
    float4_t acc = ct ? acc1 : acc0;
    int col = col0 + ct * 16 + m16;
    float bv = bias[col];
#pragma unroll
    for (int r = 0; r < 4; r++) {
      int row = row0 + quad * 4 + r;
      if (row < N) {
        float v = fmaxf(acc[r] + bv, 0.f);
        if (HALF_OUT)
          ((_Float16*)out)[(size_t)row * FDIM + col] = (_Float16)v;
        else
          ((float*)out)[(size_t)row * FDIM + col] = v;
      }
    }
  }
}

// ---------------- BN stats (fp16 input) / (fp32 input) / coeffs / apply ----------------

__global__ void stats_h_kernel(const _Float16* __restrict__ h, float* __restrict__ sum,
                               float* __restrict__ sq, int N) {
  __shared__ float red[8 * FDIM];
  int t = threadIdx.x;
  int tx = t & 31, ty = t >> 5;
  int c0 = tx * 4;
  float4 s = make_float4(0.f, 0.f, 0.f, 0.f);
  float4 q = s;
  for (int r = blockIdx.x * 8 + ty; r < N; r += gridDim.x * 8) {
    const __half2* p = (const __half2*)&h[(size_t)r * FDIM + c0];
    float2 v0 = __half22float2(p[0]);
    float2 v1 = __half22float2(p[1]);
    s.x += v0.x; s.y += v0.y; s.z += v1.x; s.w += v1.y;
    q.x += v0.x * v0.x; q.y += v0.y * v0.y; q.z += v1.x * v1.x; q.w += v1.y * v1.y;
  }
  *(float4*)&red[ty * FDIM + c0] = s;
  __syncthreads();
  if (t < FDIM) {
    float tot = 0.f;
#pragma unroll
    for (int j = 0; j < 8; j++) tot += red[j * FDIM + t];
    atomicAdd(&sum[t], tot);
  }
  __syncthreads();
  *(float4*)&red[ty * FDIM + c0] = q;
  __syncthreads();
  if (t < FDIM) {
    float tot = 0.f;
#pragma unroll
    for (int j = 0; j < 8; j++) tot += red[j * FDIM + t];
    atomicAdd(&sq[t], tot);
  }
}

__global__ void stats_f_kernel(const float* __restrict__ h, float* __restrict__ sum,
                               float* __restrict__ sq, int N) {
  __shared__ float red[8 * FDIM];
  int t = threadIdx.x;
  int tx = t & 31, ty = t >> 5;
  int c0 = tx * 4;
  float4 s = make_float4(0.f, 0.f, 0.f, 0.f);
  float4 q = s;
  for (int r = blockIdx.x * 8 + ty; r < N; r += gridDim.x * 8) {
    float4 v = *(const float4*)&h[(size_t)r * FDIM + c0];
    s.x += v.x; s.y += v.y; s.z += v.z; s.w += v.w;
    q.x += v.x * v.x; q.y += v.y * v.y; q.z += v.z * v.z; q.w += v.w * v.w;
  }
  *(float4*)&red[ty * FDIM + c0] = s;
  __syncthreads();
  if (t < FDIM) {
    float tot = 0.f;
#pragma unroll
    for (int j = 0; j < 8; j++) tot += red[j * FDIM + t];
    atomicAdd(&sum[t], tot);
  }
  __syncthreads();
  *(float4*)&red[ty * FDIM + c0] = q;
  __syncthreads();
  if (t < FDIM) {
    float tot = 0.f;
#pragma unroll
    for (int j = 0; j < 8; j++) tot += red[j * FDIM + t];
    atomicAdd(&sq[t], tot);
  }
}

__global__ void coeffs_kernel(const float* __restrict__ sum, const float* __restrict__ sq,
                              const float* __restrict__ gamma, const float* __restrict__ beta,
                              float* __restrict__ a, float* __restrict__ c, int N) {
  int t = threadIdx.x;
  if (t < FDIM) {
    float invn = 1.f / (float)N;
    float mean = sum[t] * invn;
    float var = sq[t] * invn - mean * mean;
    float rs = rsqrtf(var + 1e-5f);
    float av = gamma[t] * rs;
    a[t] = av;
    c[t] = beta[t] - mean * av;
  }
}

__global__ void apply_kernel(float* __restrict__ out, const float* __restrict__ a,
                             const float* __restrict__ c, int nvec4) {
  int i = blockIdx.x * blockDim.x + threadIdx.x;
  if (i < nvec4) {
    int c4 = i & 31;
    float4 av = ((const float4*)a)[c4];
    float4 cv = ((const float4*)c)[c4];
    float4 v = ((float4*)out)[i];
    v.x = av.x * v.x + cv.x;
    v.y = av.y * v.y + cv.y;
    v.z = av.z * v.z + cv.z;
    v.w = av.w * v.w + cv.w;
    ((float4*)out)[i] = v;
  }
}

// ---------------- launch ----------------

extern "C" void kernel_launch(void* const* d_in, const int* in_sizes, int n_in,
                              void* d_out, int out_size, void* d_ws, size_t ws_size,
                              hipStream_t stream) {
  const float* x   = (const float*)d_in[0];
  const int*   ei  = (const int*)d_in[1];
  const float* W1  = (const float*)d_in[2];
  const float* b1  = (const float*)d_in[3];
  const float* W2  = (const float*)d_in[4];
  const float* b2  = (const float*)d_in[5];
  const float* g1  = (const float*)d_in[6];
  const float* be1 = (const float*)d_in[7];
  const float* g2  = (const float*)d_in[8];
  const float* be2 = (const float*)d_in[9];
  float* out = (float*)d_out;

  const int N = in_sizes[0] / FDIM;
  const int E = in_sizes[1] / 2;
  const int* src = ei;
  const int* dst = ei + E;

  auto align256 = [](char*& q) { q = (char*)(((uintptr_t)q + 255) & ~(uintptr_t)255); };

  char* p = (char*)d_ws;
  int* deg = (int*)p;        p += (size_t)N * 4;
  float* stats = (float*)p;  p += 1024 * 4;   // s1 q1 s2 q2 a1 c1 a2 c2
  align256(p);
  int* row_start = (int*)p;  p += (size_t)N * 4; align256(p);
  int* fill_pos = (int*)p;   p += (size_t)N * 4; align256(p);
  int* csums = (int*)p;      p += 256 * 4;
  int* coffs = (int*)p;      p += 256 * 4; align256(p);
  int* ssrc = (int*)p;       p += (size_t)E * 4; align256(p);
  _Float16* xh  = (_Float16*)p; p += (size_t)N * FDIM * 2; align256(p);
  _Float16* tmp = (_Float16*)p; p += (size_t)N * FDIM * 2; align256(p);
  _Float16* h1  = (_Float16*)p; p += (size_t)N * FDIM * 2; align256(p);
  _Float16* W1h = (_Float16*)p; p += FDIM * FDIM * 2;
  _Float16* W2h = (_Float16*)p; p += FDIM * FDIM * 2;

  float* s1 = stats + 0,   *q1 = stats + 128;
  float* s2 = stats + 256, *q2 = stats + 384;
  float* a1 = stats + 512, *c1 = stats + 640;
  float* a2 = stats + 768, *c2 = stats + 896;

  const int nchunk = (N + 1023) / 1024;
  const int ntiles = (N + 15) / 16;

  // CSR build + conversions
  int zn = N + 1024;  // deg + stats region (contiguous)
  zero_kernel<<<(zn + 255) / 256, 256, 0, stream>>>(deg, zn);
  hist_kernel<<<(E + 255) / 256, 256, 0, stream>>>(dst, deg, E);
  cvt_f2h_kernel<<<(N * 32 + 255) / 256, 256, 0, stream>>>(x, xh, N * 32);
  cvt_f2h_kernel<<<(FDIM * 32 + 255) / 256, 256, 0, stream>>>(W1, W1h, FDIM * 32);
  cvt_f2h_kernel<<<(FDIM * 32 + 255) / 256, 256, 0, stream>>>(W2, W2h, FDIM * 32);
  scan1_kernel<<<nchunk, 256, 0, stream>>>(deg, csums, N);
  scan2_kernel<<<1, 64, 0, stream>>>(csums, coffs, nchunk);
  scan3_kernel<<<nchunk, 256, 0, stream>>>(deg, coffs, row_start, fill_pos, N);
  place_kernel<<<(E + 255) / 256, 256, 0, stream>>>(src, dst, fill_pos, ssrc, E);

  // layer 1
  agg1_kernel<<<(N + 3) / 4, 256, 0, stream>>>((const unsigned*)xh, row_start, deg, ssrc,
                                               (unsigned*)tmp, N);
  gemm_mfma_kernel<true><<<ntiles, 256, 0, stream>>>(tmp, W1h, b1, h1, N);
  stats_h_kernel<<<256, 256, 0, stream>>>(h1, s1, q1, N);
  coeffs_kernel<<<1, 128, 0, stream>>>(s1, q1, g1, be1, a1, c1, N);

  // layer 2 (BN1 folded into aggregation)
  agg2_kernel<<<(N + 3) / 4, 256, 0, stream>>>((const unsigned*)h1, row_start, deg, ssrc,
                                               a1, c1, (unsigned*)tmp, N);
  gemm_mfma_kernel<false><<<ntiles, 256, 0, stream>>>(tmp, W2h, b2, out, N);
  stats_f_kernel<<<256, 256, 0, stream>>>(out, s2, q2, N);
  coeffs_kernel<<<1, 128, 0, stream>>>(s2, q2, g2, be2, a2, c2, N);

  // BN2 in place on out
  int nvec4 = N * 32;
  apply_kernel<<<(nvec4 + 255) / 256, 256, 0, stream>>>(out, a2, c2, nvec4);
}